// Round 1
// baseline (8511.926 us; speedup 1.0000x reference)
//
#include <hip/hip_runtime.h>
#include <math.h>

#define NB 32
#define NN 3136
#define CD 320
#define NH 5
#define CN 400
#define NKEY 196
#define DQ 80
#define DV 64
#define SCALE_F 0.11180339887498949f

// ---------------------------------------------------------------------------
// Kernel 1: dwconv(4x4,s4,groups=320) + 1x1 conv 320->400 + LayerNorm + GELU
// -> xs [B,196,400].  grid (14, 32): blockIdx.x = output row oh, y = batch.
// ---------------------------------------------------------------------------
__global__ __launch_bounds__(256) void k_spatial(
    const float* __restrict__ x, const float* __restrict__ dw_w,
    const float* __restrict__ dw_b, const float* __restrict__ pw_w,
    const float* __restrict__ pw_b, const float* __restrict__ ln_g,
    const float* __restrict__ ln_b, float* __restrict__ xs) {
  const int oh = blockIdx.x, b = blockIdx.y, tid = threadIdx.x;
  __shared__ float dwc[14][321];   // dwconv result per (ow, c)
  __shared__ float pre[14][401];   // pre-LN pointwise result per (ow, o)
  const float* xb = x + (size_t)b * NN * CD;

  // depthwise conv: 14 output cols x 320 channels
  for (int idx = tid; idx < 14 * 320; idx += 256) {
    const int p = idx / 320, c = idx - p * 320;
    float acc = dw_b[c];
#pragma unroll
    for (int i = 0; i < 4; i++) {
#pragma unroll
      for (int j = 0; j < 4; j++) {
        const int pix = (oh * 4 + i) * 56 + p * 4 + j;
        acc += xb[(size_t)pix * CD + c] * dw_w[c * 16 + i * 4 + j];
      }
    }
    dwc[p][c] = acc;
  }
  __syncthreads();

  // pointwise 320 -> 400
  for (int o = tid; o < 400; o += 256) {
    float acc[14];
    const float bias = pw_b[o];
#pragma unroll
    for (int p = 0; p < 14; p++) acc[p] = bias;
    const float* wrow = pw_w + (size_t)o * 320;
    for (int c = 0; c < 320; c++) {
      const float w = wrow[c];
#pragma unroll
      for (int p = 0; p < 14; p++) acc[p] += dwc[p][c] * w;
    }
#pragma unroll
    for (int p = 0; p < 14; p++) pre[p][o] = acc[p];
  }
  __syncthreads();

  // LayerNorm (400) + exact GELU; one wave per position
  const int wave = tid >> 6, lane = tid & 63;
  for (int p = wave; p < 14; p += 4) {
    float s = 0.f, ss = 0.f;
    for (int o = lane; o < 400; o += 64) {
      const float v = pre[p][o];
      s += v;
      ss += v * v;
    }
#pragma unroll
    for (int off = 32; off > 0; off >>= 1) {
      s += __shfl_xor(s, off);
      ss += __shfl_xor(ss, off);
    }
    const float mu = s * (1.f / 400.f);
    const float var = ss * (1.f / 400.f) - mu * mu;
    const float rstd = rsqrtf(var + 1e-5f);
    float* orow = xs + ((size_t)(b * NKEY + oh * 14 + p)) * CN;
    for (int o = lane; o < 400; o += 64) {
      const float v = (pre[p][o] - mu) * rstd * ln_g[o] + ln_b[o];
      orow[o] = 0.5f * v * (1.f + erff(v * 0.70710678118654752f));
    }
  }
}

// ---------------------------------------------------------------------------
// Kernel 2: k = xs @ k_w [400x400], v = xs @ v_w [400x320].
// grid (7, 32): 28 rows of xs per block. Register tile 14 rows x 4 outputs.
// ---------------------------------------------------------------------------
__global__ __launch_bounds__(256) void k_kv(
    const float* __restrict__ xs, const float* __restrict__ k_w,
    const float* __restrict__ v_w, float* __restrict__ kb,
    float* __restrict__ vb) {
  const int b = blockIdx.y, r0 = blockIdx.x * 28, tid = threadIdx.x;
  __shared__ float xls[28 * 401];
  for (int idx = tid; idx < 28 * 400; idx += 256) {
    const int r = idx / 400, c = idx - r * 400;
    xls[r * 401 + c] = xs[((size_t)(b * NKEY + r0 + r)) * CN + c];
  }
  __syncthreads();

  for (int tt = tid; tt < 360; tt += 256) {  // 2 rgroups x 180 o-groups
    const int rg = tt & 1, og = tt >> 1;
    const int o0 = og * 4;                   // o0 < 400: k,  else v
    const bool isk = o0 < 400;
    const float* W = isk ? (k_w + o0) : (v_w + (o0 - 400));
    const int wstride = isk ? 400 : 320;
    float acc[14][4];
#pragma unroll
    for (int r = 0; r < 14; r++)
#pragma unroll
      for (int q = 0; q < 4; q++) acc[r][q] = 0.f;

    for (int c = 0; c < 400; c++) {
      const float4 w4 = *(const float4*)(W + (size_t)c * wstride);
#pragma unroll
      for (int r = 0; r < 14; r++) {
        const float xv = xls[(rg * 14 + r) * 401 + c];
        acc[r][0] += xv * w4.x;
        acc[r][1] += xv * w4.y;
        acc[r][2] += xv * w4.z;
        acc[r][3] += xv * w4.w;
      }
    }
    if (isk) {
      float* dst = kb + ((size_t)(b * NKEY + r0 + rg * 14)) * CN + o0;
#pragma unroll
      for (int r = 0; r < 14; r++)
        *(float4*)(dst + (size_t)r * CN) =
            make_float4(acc[r][0], acc[r][1], acc[r][2], acc[r][3]);
    } else {
      float* dst = vb + ((size_t)(b * NKEY + r0 + rg * 14)) * CD + (o0 - 400);
#pragma unroll
      for (int r = 0; r < 14; r++)
        *(float4*)(dst + (size_t)r * CD) =
            make_float4(acc[r][0], acc[r][1], acc[r][2], acc[r][3]);
    }
  }
}

// ---------------------------------------------------------------------------
// Kernel 3: fused q-projection + attention for one (b, head, 32-query tile).
// grid (98, 5, 32). LDS = 14080 floats = 55 KB (under 64 KB static limit).
// ---------------------------------------------------------------------------
__global__ __launch_bounds__(256) void k_attn(
    const float* __restrict__ x, const float* __restrict__ q_w,
    const float* __restrict__ kb, const float* __restrict__ vb,
    float* __restrict__ out) {
  const int qt = blockIdx.x, h = blockIdx.y, b = blockIdx.z;
  const int tid = threadIdx.x;
  const int q0 = qt * 32;

  __shared__ float sm[14080];
  float* q_s = sm;            // [32][81]  = 2592
  float* Ss = sm + 2592;      // [32][197] = 6304 (scores / softmax P)
  float* st = sm + 8896;      // [64][81] k-stage / [64][68] v-stage = 5184

  // ---- Phase A: q_tile[32][80] = x[b, q0..q0+31, :] @ q_w[:, h*80..+80)
  {
    float* xA = Ss;          // [32][65] = 2080  (aliases score region)
    float* wB = Ss + 2080;   // [64][81] = 5184  (spans into st; ok, barriered)
    const int r2 = tid >> 4;     // 16 groups of 2 rows
    const int l16 = tid & 15;    // o = l16 + 16*k, k<5
    float acc[2][5];
#pragma unroll
    for (int i = 0; i < 2; i++)
#pragma unroll
      for (int k = 0; k < 5; k++) acc[i][k] = 0.f;

    for (int c0 = 0; c0 < 320; c0 += 64) {
      for (int idx = tid; idx < 32 * 64; idx += 256) {
        const int r = idx >> 6, c = idx & 63;
        xA[r * 65 + c] = x[((size_t)(b * NN + q0 + r)) * CD + c0 + c];
      }
      for (int idx = tid; idx < 64 * 80; idx += 256) {
        const int c = idx / 80, o = idx - c * 80;
        wB[c * 81 + o] = q_w[(size_t)(c0 + c) * CN + h * DQ + o];
      }
      __syncthreads();
      for (int c = 0; c < 64; c++) {
        float xv[2];
#pragma unroll
        for (int i = 0; i < 2; i++) xv[i] = xA[(r2 * 2 + i) * 65 + c];
#pragma unroll
        for (int k = 0; k < 5; k++) {
          const float wv = wB[c * 81 + l16 + 16 * k];
#pragma unroll
          for (int i = 0; i < 2; i++) acc[i][k] += xv[i] * wv;
        }
      }
      __syncthreads();
    }
#pragma unroll
    for (int i = 0; i < 2; i++)
#pragma unroll
      for (int k = 0; k < 5; k++)
        q_s[(r2 * 2 + i) * 81 + l16 + 16 * k] = acc[i][k];
  }
  __syncthreads();  // q_s ready; Ss/st free for reuse

  // ---- Phase B: S[32][196] = scale * q_tile @ K^T, K staged in 64-row chunks
  {
    const int mg = tid >> 5;  // 8 groups of 4 rows
    const int jp = tid & 31;  // 32 pairs of 2 keys
    const float* kbh = kb + ((size_t)b * NKEY) * CN + h * DQ;
    for (int j0 = 0; j0 < NKEY; j0 += 64) {
      const int nj = min(64, NKEY - j0);
      for (int idx = tid; idx < nj * 80; idx += 256) {
        const int jj = idx / 80, c = idx - jj * 80;
        st[jj * 81 + c] = kbh[(size_t)(j0 + jj) * CN + c];
      }
      __syncthreads();
      float a2[4][2];
#pragma unroll
      for (int i = 0; i < 4; i++) { a2[i][0] = 0.f; a2[i][1] = 0.f; }
      for (int c = 0; c < 80; c++) {
        const float k0v = st[(jp * 2) * 81 + c];
        const float k1v = st[(jp * 2 + 1) * 81 + c];
#pragma unroll
        for (int i = 0; i < 4; i++) {
          const float qv = q_s[(mg * 4 + i) * 81 + c];
          a2[i][0] += qv * k0v;
          a2[i][1] += qv * k1v;
        }
      }
#pragma unroll
      for (int i = 0; i < 4; i++)
#pragma unroll
        for (int jj = 0; jj < 2; jj++)
          if (jp * 2 + jj < nj)
            Ss[(mg * 4 + i) * 197 + j0 + jp * 2 + jj] = a2[i][jj] * SCALE_F;
      __syncthreads();
    }
  }

  // ---- Phase C: softmax over 196 keys; 8 lanes per query row
  {
    const int m = tid >> 3, o8 = tid & 7;
    float mx = -1e30f;
    for (int jj = 0; jj < 25; jj++) {
      const int j = o8 + 8 * jj;
      if (j < NKEY) mx = fmaxf(mx, Ss[m * 197 + j]);
    }
    mx = fmaxf(mx, __shfl_xor(mx, 1));
    mx = fmaxf(mx, __shfl_xor(mx, 2));
    mx = fmaxf(mx, __shfl_xor(mx, 4));
    float sum = 0.f;
    for (int jj = 0; jj < 25; jj++) {
      const int j = o8 + 8 * jj;
      if (j < NKEY) {
        const float e = expf(Ss[m * 197 + j] - mx);
        Ss[m * 197 + j] = e;
        sum += e;
      }
    }
    sum += __shfl_xor(sum, 1);
    sum += __shfl_xor(sum, 2);
    sum += __shfl_xor(sum, 4);
    const float inv = 1.f / sum;
    for (int jj = 0; jj < 25; jj++) {
      const int j = o8 + 8 * jj;
      if (j < NKEY) Ss[m * 197 + j] *= inv;
    }
  }
  __syncthreads();

  // ---- Phase D: out[32][64] = P @ V, V staged in 64-row chunks
  {
    const int mg = tid >> 4;  // 16 groups of 2 rows
    const int og = tid & 15;  // 16 groups of 4 cols
    const float* vbh = vb + ((size_t)b * NKEY) * CD + h * DV;
    float acc[2][4];
#pragma unroll
    for (int i = 0; i < 2; i++)
#pragma unroll
      for (int q = 0; q < 4; q++) acc[i][q] = 0.f;

    for (int j0 = 0; j0 < NKEY; j0 += 64) {
      const int nj = min(64, NKEY - j0);
      for (int idx = tid; idx < nj * 64; idx += 256) {
        const int jj = idx >> 6, c = idx & 63;
        st[jj * 68 + c] = vbh[(size_t)(j0 + jj) * CD + c];
      }
      __syncthreads();
      for (int jj = 0; jj < nj; jj++) {
        const float4 v4 = *(const float4*)(st + jj * 68 + og * 4);
#pragma unroll
        for (int i = 0; i < 2; i++) {
          const float p = Ss[(mg * 2 + i) * 197 + j0 + jj];
          acc[i][0] += p * v4.x;
          acc[i][1] += p * v4.y;
          acc[i][2] += p * v4.z;
          acc[i][3] += p * v4.w;
        }
      }
      __syncthreads();
    }
#pragma unroll
    for (int i = 0; i < 2; i++) {
      *(float4*)(out + ((size_t)(b * NN + q0 + mg * 2 + i)) * CD + h * DV +
                 og * 4) =
          make_float4(acc[i][0], acc[i][1], acc[i][2], acc[i][3]);
    }
  }
}

// ---------------------------------------------------------------------------
// Kernel 4: in-place output projection: out = out @ proj_w + proj_b.
// grid 3136 blocks x 32 rows. Rows staged to LDS before overwrite.
// ---------------------------------------------------------------------------
__global__ __launch_bounds__(256) void k_proj(float* __restrict__ out,
                                              const float* __restrict__ proj_w,
                                              const float* __restrict__ proj_b) {
  const size_t r0 = (size_t)blockIdx.x * 32;
  const int tid = threadIdx.x;
  __shared__ float in_s[32 * 321];
  for (int idx = tid; idx < 32 * 320; idx += 256) {
    const int r = idx / 320, c = idx - r * 320;
    in_s[r * 321 + c] = out[(r0 + r) * CD + c];
  }
  __syncthreads();
  for (int tt = tid; tt < 320; tt += 256) {  // 2 rgroups x 160 o-pairs
    const int rg = tt & 1, og = tt >> 1;
    const int o0 = og * 2;
    float acc[16][2];
#pragma unroll
    for (int r = 0; r < 16; r++) { acc[r][0] = 0.f; acc[r][1] = 0.f; }
    for (int c = 0; c < 320; c++) {
      const float2 w2 = *(const float2*)(proj_w + (size_t)c * CD + o0);
#pragma unroll
      for (int r = 0; r < 16; r++) {
        const float xv = in_s[(rg * 16 + r) * 321 + c];
        acc[r][0] += xv * w2.x;
        acc[r][1] += xv * w2.y;
      }
    }
    const float2 b2 = *(const float2*)(proj_b + o0);
#pragma unroll
    for (int r = 0; r < 16; r++)
      *(float2*)(out + (r0 + rg * 16 + r) * CD + o0) =
          make_float2(acc[r][0] + b2.x, acc[r][1] + b2.y);
  }
}

// ---------------------------------------------------------------------------
extern "C" void kernel_launch(void* const* d_in, const int* in_sizes, int n_in,
                              void* d_out, int out_size, void* d_ws,
                              size_t ws_size, hipStream_t stream) {
  const float* x = (const float*)d_in[0];
  // d_in[1] = H, d_in[2] = W (fixed 56x56, unused)
  const float* dw_w = (const float*)d_in[3];
  const float* dw_b = (const float*)d_in[4];
  const float* pw_w = (const float*)d_in[5];
  const float* pw_b = (const float*)d_in[6];
  const float* ln_g = (const float*)d_in[7];
  const float* ln_b = (const float*)d_in[8];
  const float* q_w = (const float*)d_in[9];
  const float* k_w = (const float*)d_in[10];
  const float* v_w = (const float*)d_in[11];
  const float* proj_w = (const float*)d_in[12];
  const float* proj_b = (const float*)d_in[13];
  float* out = (float*)d_out;

  float* ws = (float*)d_ws;
  float* xs = ws;                 // [32][196][400] = 2,508,800 f
  float* kbuf = ws + 2508800;     // [32][196][400] = 2,508,800 f
  float* vbuf = ws + 5017600;     // [32][196][320] = 2,007,040 f
                                  // total 28.1 MB of ws

  k_spatial<<<dim3(14, 32), 256, 0, stream>>>(x, dw_w, dw_b, pw_w, pw_b, ln_g,
                                              ln_b, xs);
  k_kv<<<dim3(7, 32), 256, 0, stream>>>(xs, k_w, v_w, kbuf, vbuf);
  k_attn<<<dim3(98, 5, 32), 256, 0, stream>>>(x, q_w, kbuf, vbuf, out);
  k_proj<<<3136, 256, 0, stream>>>(out, proj_w, proj_b);
}

// Round 2
// 1073.701 us; speedup vs baseline: 7.9276x; 7.9276x over previous
//
#include <hip/hip_runtime.h>
#include <math.h>

#define NB 32
#define NN 3136
#define CD 320
#define NH 5
#define CN 400
#define NKEY 196
#define DQ 80
#define DV 64
#define SCALE_F 0.11180339887498949f

typedef __bf16 bf16x8 __attribute__((ext_vector_type(8)));
typedef float f32x4 __attribute__((ext_vector_type(4)));
typedef unsigned short u16;
typedef unsigned int u32;

__device__ __forceinline__ u16 f2bf(float f) {
  u32 u = __float_as_uint(f);
  u += 0x7fffu + ((u >> 16) & 1u);  // round-to-nearest-even
  return (u16)(u >> 16);
}

// ---------------------------------------------------------------------------
// Prep: transpose q_w [320,400] -> qwT bf16 [400][320]; proj_w -> pwT [320][320]
// ---------------------------------------------------------------------------
__global__ void k_prep(const float* __restrict__ q_w,
                       const float* __restrict__ proj_w, u16* __restrict__ qwT,
                       u16* __restrict__ pwT) {
  const int i0 = blockIdx.x * 256 + threadIdx.x;
  const int stride = gridDim.x * 256;
  for (int idx = i0; idx < 400 * 320; idx += stride) {
    const int o = idx / 320, c = idx - o * 320;
    qwT[idx] = f2bf(q_w[(size_t)c * 400 + o]);
  }
  for (int idx = i0; idx < 320 * 320; idx += stride) {
    const int o = idx / 320, c = idx - o * 320;
    pwT[idx] = f2bf(proj_w[(size_t)c * 320 + o]);
  }
}

// ---------------------------------------------------------------------------
// Kernel 1: dwconv(4x4,s4,groups=320) + 1x1 conv 320->400 + LayerNorm + GELU
// -> xs [B,196,400] fp32.  grid (14, 32).
// ---------------------------------------------------------------------------
__global__ __launch_bounds__(256) void k_spatial(
    const float* __restrict__ x, const float* __restrict__ dw_w,
    const float* __restrict__ dw_b, const float* __restrict__ pw_w,
    const float* __restrict__ pw_b, const float* __restrict__ ln_g,
    const float* __restrict__ ln_b, float* __restrict__ xs) {
  const int oh = blockIdx.x, b = blockIdx.y, tid = threadIdx.x;
  __shared__ float dwc[14][321];
  __shared__ float pre[14][401];
  const float* xb = x + (size_t)b * NN * CD;

  for (int idx = tid; idx < 14 * 320; idx += 256) {
    const int p = idx / 320, c = idx - p * 320;
    float acc = dw_b[c];
#pragma unroll
    for (int i = 0; i < 4; i++) {
#pragma unroll
      for (int j = 0; j < 4; j++) {
        const int pix = (oh * 4 + i) * 56 + p * 4 + j;
        acc += xb[(size_t)pix * CD + c] * dw_w[c * 16 + i * 4 + j];
      }
    }
    dwc[p][c] = acc;
  }
  __syncthreads();

  for (int o = tid; o < 400; o += 256) {
    float acc[14];
    const float bias = pw_b[o];
#pragma unroll
    for (int p = 0; p < 14; p++) acc[p] = bias;
    const float* wrow = pw_w + (size_t)o * 320;
    for (int c = 0; c < 320; c++) {
      const float w = wrow[c];
#pragma unroll
      for (int p = 0; p < 14; p++) acc[p] += dwc[p][c] * w;
    }
#pragma unroll
    for (int p = 0; p < 14; p++) pre[p][o] = acc[p];
  }
  __syncthreads();

  const int wave = tid >> 6, lane = tid & 63;
  for (int p = wave; p < 14; p += 4) {
    float s = 0.f, ss = 0.f;
    for (int o = lane; o < 400; o += 64) {
      const float v = pre[p][o];
      s += v;
      ss += v * v;
    }
#pragma unroll
    for (int off = 32; off > 0; off >>= 1) {
      s += __shfl_xor(s, off);
      ss += __shfl_xor(ss, off);
    }
    const float mu = s * (1.f / 400.f);
    const float var = ss * (1.f / 400.f) - mu * mu;
    const float rstd = rsqrtf(var + 1e-5f);
    float* orow = xs + ((size_t)(b * NKEY + oh * 14 + p)) * CN;
    for (int o = lane; o < 400; o += 64) {
      const float v = (pre[p][o] - mu) * rstd * ln_g[o] + ln_b[o];
      orow[o] = 0.5f * v * (1.f + erff(v * 0.70710678118654752f));
    }
  }
}

// ---------------------------------------------------------------------------
// Kernel 2: k = xs @ k_w -> kb bf16 [32][196][400];
//           v = xs @ v_w -> vt bf16 transposed [32][320][224] (key-minor).
// ---------------------------------------------------------------------------
__global__ __launch_bounds__(256) void k_kv(const float* __restrict__ xs,
                                            const float* __restrict__ k_w,
                                            const float* __restrict__ v_w,
                                            u16* __restrict__ kb,
                                            u16* __restrict__ vt) {
  const int b = blockIdx.y, r0 = blockIdx.x * 28, tid = threadIdx.x;
  __shared__ float xls[28 * 401];
  for (int idx = tid; idx < 28 * 400; idx += 256) {
    const int r = idx / 400, c = idx - r * 400;
    xls[r * 401 + c] = xs[((size_t)(b * NKEY + r0 + r)) * CN + c];
  }
  __syncthreads();

  for (int tt = tid; tt < 360; tt += 256) {
    const int rg = tt & 1, og = tt >> 1;
    const int o0 = og * 4;
    const bool isk = o0 < 400;
    const float* W = isk ? (k_w + o0) : (v_w + (o0 - 400));
    const int wstride = isk ? 400 : 320;
    float acc[14][4];
#pragma unroll
    for (int r = 0; r < 14; r++)
#pragma unroll
      for (int q = 0; q < 4; q++) acc[r][q] = 0.f;

    for (int c = 0; c < 400; c++) {
      const float4 w4 = *(const float4*)(W + (size_t)c * wstride);
#pragma unroll
      for (int r = 0; r < 14; r++) {
        const float xv = xls[(rg * 14 + r) * 401 + c];
        acc[r][0] += xv * w4.x;
        acc[r][1] += xv * w4.y;
        acc[r][2] += xv * w4.z;
        acc[r][3] += xv * w4.w;
      }
    }
    if (isk) {
#pragma unroll
      for (int r = 0; r < 14; r++) {
        ushort4 s4 = make_ushort4(f2bf(acc[r][0]), f2bf(acc[r][1]),
                                  f2bf(acc[r][2]), f2bf(acc[r][3]));
        *(ushort4*)(kb + ((size_t)(b * NKEY + r0 + rg * 14 + r)) * CN + o0) = s4;
      }
    } else {
      const int vo = o0 - 400;
#pragma unroll
      for (int r = 0; r < 14; r++) {
        const int key = r0 + rg * 14 + r;
#pragma unroll
        for (int q = 0; q < 4; q++)
          vt[((size_t)(b * 320 + vo + q)) * 224 + key] = f2bf(acc[r][q]);
      }
    }
  }
}

// ---------------------------------------------------------------------------
// Kernel 3: fused q-proj + attention, MFMA bf16. Block = (h, 64-query tile, b).
// LDS regions (u16 offsets, 29696 total = 59392 B):
//   phase A: xch @6656 [64][72], wch @11264 [80][72]; q_s @0 [64][104]
//   phase B: q_s @0, Ks @6656 [196(+12 overread)][104]
//   phase D: P @0 [64][232], Vt @14848 [64][232]
// ---------------------------------------------------------------------------
__global__ __launch_bounds__(256) void k_attn(const float* __restrict__ x,
                                              const u16* __restrict__ qwT,
                                              const u16* __restrict__ kb,
                                              const u16* __restrict__ vt,
                                              float* __restrict__ out) {
  const int h = blockIdx.x, qt = blockIdx.y, b = blockIdx.z;
  const int tid = threadIdx.x;
  const int lane = tid & 63, wv = tid >> 6;
  const int quad = lane >> 4, l15 = lane & 15;
  const int q0 = qt * 64;
  const int m0 = wv * 16;
  const f32x4 fz = {0.f, 0.f, 0.f, 0.f};

  __shared__ u16 sm[29696];

  // ---- Phase A: q[64][80] = x_tile[64][320] @ q_w[:, h*80:+80)
  f32x4 qacc[5];
#pragma unroll
  for (int n = 0; n < 5; n++) qacc[n] = fz;
  {
    u16* xch = sm + 6656;
    u16* wch = sm + 11264;
    for (int c0 = 0; c0 < 320; c0 += 64) {
      for (int idx = tid; idx < 64 * 16; idx += 256) {
        const int r = idx >> 4, c4 = idx & 15;
        const float4 v =
            *(const float4*)(x + ((size_t)(b * NN + q0 + r)) * CD + c0 + c4 * 4);
        *(ushort4*)(xch + r * 72 + c4 * 4) =
            make_ushort4(f2bf(v.x), f2bf(v.y), f2bf(v.z), f2bf(v.w));
      }
      for (int idx = tid; idx < 80 * 16; idx += 256) {
        const int r = idx >> 4, c4 = idx & 15;
        *(ushort4*)(wch + r * 72 + c4 * 4) =
            *(const ushort4*)(qwT + (size_t)(h * DQ + r) * CD + c0 + c4 * 4);
      }
      __syncthreads();
#pragma unroll
      for (int ks = 0; ks < 2; ks++) {
        const bf16x8 a =
            *(const bf16x8*)(xch + (m0 + l15) * 72 + ks * 32 + quad * 8);
#pragma unroll
        for (int n = 0; n < 5; n++) {
          const bf16x8 bf =
              *(const bf16x8*)(wch + (n * 16 + l15) * 72 + ks * 32 + quad * 8);
          qacc[n] = __builtin_amdgcn_mfma_f32_16x16x32_bf16(a, bf, qacc[n], 0, 0, 0);
        }
      }
      __syncthreads();
    }
  }
  // write q_s [64][104] (C-layout -> row-major bf16), zero pad cols 80..95
  {
    u16* q_s = sm;
#pragma unroll
    for (int n = 0; n < 5; n++)
#pragma unroll
      for (int r = 0; r < 4; r++)
        q_s[(m0 + quad * 4 + r) * 104 + n * 16 + l15] = f2bf(qacc[n][r]);
#pragma unroll
    for (int r = 0; r < 4; r++) q_s[(m0 + l15) * 104 + 80 + quad * 4 + r] = 0;
  }
  // stage Ks [196][104]: cols 0..79 from kb head slice, 80..95 zero
  {
    u16* Ks = sm + 6656;
    for (int idx = tid; idx < 196 * 12; idx += 256) {
      const int key = idx / 12, g = idx - key * 12;
      if (g < 10)
        *(uint4*)(Ks + key * 104 + g * 8) = *(const uint4*)(
            kb + ((size_t)(b * NKEY + key)) * CN + h * DQ + g * 8);
      else
        *(uint4*)(Ks + key * 104 + 80 + (g - 10) * 8) = make_uint4(0, 0, 0, 0);
    }
  }
  __syncthreads();

  // ---- Phase B: S[64][208] = q @ K^T (13 N-tiles, K=96)
  f32x4 sacc[13];
#pragma unroll
  for (int n = 0; n < 13; n++) sacc[n] = fz;
  {
    const u16* q_s = sm;
    const u16* Ks = sm + 6656;
    bf16x8 a[3];
#pragma unroll
    for (int ks = 0; ks < 3; ks++)
      a[ks] = *(const bf16x8*)(q_s + (m0 + l15) * 104 + ks * 32 + quad * 8);
#pragma unroll
    for (int n = 0; n < 13; n++)
#pragma unroll
      for (int ks = 0; ks < 3; ks++) {
        const bf16x8 bf =
            *(const bf16x8*)(Ks + (n * 16 + l15) * 104 + ks * 32 + quad * 8);
        sacc[n] = __builtin_amdgcn_mfma_f32_16x16x32_bf16(a[ks], bf, sacc[n], 0, 0, 0);
      }
  }

  // ---- Phase C: softmax in registers (C-layout; 16-lane groups share rows)
  {
    float mx[4] = {-1e30f, -1e30f, -1e30f, -1e30f};
#pragma unroll
    for (int n = 0; n < 13; n++)
#pragma unroll
      for (int r = 0; r < 4; r++) {
        const float s =
            (n == 12 && l15 >= 4) ? -1e30f : sacc[n][r] * SCALE_F;
        sacc[n][r] = s;
        mx[r] = fmaxf(mx[r], s);
      }
#pragma unroll
    for (int r = 0; r < 4; r++) {
      mx[r] = fmaxf(mx[r], __shfl_xor(mx[r], 1));
      mx[r] = fmaxf(mx[r], __shfl_xor(mx[r], 2));
      mx[r] = fmaxf(mx[r], __shfl_xor(mx[r], 4));
      mx[r] = fmaxf(mx[r], __shfl_xor(mx[r], 8));
    }
    float sum[4] = {0.f, 0.f, 0.f, 0.f};
#pragma unroll
    for (int n = 0; n < 13; n++)
#pragma unroll
      for (int r = 0; r < 4; r++) {
        const float e = __expf(sacc[n][r] - mx[r]);
        sacc[n][r] = e;
        sum[r] += e;
      }
#pragma unroll
    for (int r = 0; r < 4; r++) {
      sum[r] += __shfl_xor(sum[r], 1);
      sum[r] += __shfl_xor(sum[r], 2);
      sum[r] += __shfl_xor(sum[r], 4);
      sum[r] += __shfl_xor(sum[r], 8);
    }
#pragma unroll
    for (int r = 0; r < 4; r++) {
      const float inv = 1.f / sum[r];
#pragma unroll
      for (int n = 0; n < 13; n++) sacc[n][r] *= inv;
    }
  }
  __syncthreads();  // all waves done reading q_s/Ks

  // ---- write P bf16 [64][232] (zero-pad cols 196..223) + stage Vt [64][232]
  {
    u16* P = sm;
    u16* Vt = sm + 14848;
#pragma unroll
    for (int n = 0; n < 13; n++) {
      if (n == 12 && l15 >= 4) continue;
#pragma unroll
      for (int r = 0; r < 4; r++)
        P[(m0 + quad * 4 + r) * 232 + n * 16 + l15] = f2bf(sacc[n][r]);
    }
    {
      const int row = m0 + (lane >> 2), c0 = 196 + (lane & 3) * 7;
#pragma unroll
      for (int t = 0; t < 7; t++) P[row * 232 + c0 + t] = 0;
    }
    for (int idx = tid; idx < 64 * 28; idx += 256) {
      const int o = idx / 28, g = idx - o * 28;
      *(uint4*)(Vt + o * 232 + g * 8) = *(const uint4*)(
          vt + ((size_t)(b * 320 + h * 64 + o)) * 224 + g * 8);
    }
  }
  __syncthreads();

  // ---- Phase D: O[64][64] = P[64][224] @ V[224][64]
  f32x4 oacc[4];
#pragma unroll
  for (int n = 0; n < 4; n++) oacc[n] = fz;
  {
    const u16* P = sm;
    const u16* Vt = sm + 14848;
    for (int kk = 0; kk < 7; kk++) {
      const bf16x8 a =
          *(const bf16x8*)(P + (m0 + l15) * 232 + kk * 32 + quad * 8);
#pragma unroll
      for (int n = 0; n < 4; n++) {
        const bf16x8 bf =
            *(const bf16x8*)(Vt + (n * 16 + l15) * 232 + kk * 32 + quad * 8);
        oacc[n] = __builtin_amdgcn_mfma_f32_16x16x32_bf16(a, bf, oacc[n], 0, 0, 0);
      }
    }
  }
#pragma unroll
  for (int n = 0; n < 4; n++)
#pragma unroll
    for (int r = 0; r < 4; r++)
      out[((size_t)(b * NN + q0 + m0 + quad * 4 + r)) * CD + h * 64 + n * 16 +
          l15] = oacc[n][r];
}

// ---------------------------------------------------------------------------
// Kernel 4: in-place out = out @ proj_w + proj_b, MFMA bf16. 64 rows/block.
// All reads (chunk staging) complete before the end-of-kernel writes.
// ---------------------------------------------------------------------------
__global__ __launch_bounds__(256) void k_proj(float* __restrict__ out,
                                              const u16* __restrict__ pwT,
                                              const float* __restrict__ proj_b) {
  const int tid = threadIdx.x;
  const int lane = tid & 63, wv = tid >> 6;
  const int quad = lane >> 4, l15 = lane & 15;
  const size_t r0 = (size_t)blockIdx.x * 64;
  const int m0 = wv * 16;
  const f32x4 fz = {0.f, 0.f, 0.f, 0.f};

  __shared__ u16 sm[64 * 72 + 320 * 72];  // 27648 u16 = 55296 B
  u16* xch = sm;         // [64][72]
  u16* wch = sm + 4608;  // [320][72]

  f32x4 acc[20];
#pragma unroll
  for (int n = 0; n < 20; n++) acc[n] = fz;

  for (int c0 = 0; c0 < 320; c0 += 64) {
    for (int idx = tid; idx < 64 * 16; idx += 256) {
      const int r = idx >> 4, c4 = idx & 15;
      const float4 v = *(const float4*)(out + (r0 + r) * CD + c0 + c4 * 4);
      *(ushort4*)(xch + r * 72 + c4 * 4) =
          make_ushort4(f2bf(v.x), f2bf(v.y), f2bf(v.z), f2bf(v.w));
    }
    for (int idx = tid; idx < 320 * 8; idx += 256) {
      const int r = idx >> 3, g = idx & 7;
      *(uint4*)(wch + r * 72 + g * 8) =
          *(const uint4*)(pwT + (size_t)r * CD + c0 + g * 8);
    }
    __syncthreads();
#pragma unroll
    for (int ks = 0; ks < 2; ks++) {
      const bf16x8 a =
          *(const bf16x8*)(xch + (m0 + l15) * 72 + ks * 32 + quad * 8);
#pragma unroll
      for (int n = 0; n < 20; n++) {
        const bf16x8 bf =
            *(const bf16x8*)(wch + (n * 16 + l15) * 72 + ks * 32 + quad * 8);
        acc[n] = __builtin_amdgcn_mfma_f32_16x16x32_bf16(a, bf, acc[n], 0, 0, 0);
      }
    }
    __syncthreads();
  }
#pragma unroll
  for (int n = 0; n < 20; n++) {
    const float pb = proj_b[n * 16 + l15];
#pragma unroll
    for (int r = 0; r < 4; r++)
      out[(r0 + m0 + quad * 4 + r) * CD + n * 16 + l15] = acc[n][r] + pb;
  }
}

// ---------------------------------------------------------------------------
extern "C" void kernel_launch(void* const* d_in, const int* in_sizes, int n_in,
                              void* d_out, int out_size, void* d_ws,
                              size_t ws_size, hipStream_t stream) {
  const float* x = (const float*)d_in[0];
  const float* dw_w = (const float*)d_in[3];
  const float* dw_b = (const float*)d_in[4];
  const float* pw_w = (const float*)d_in[5];
  const float* pw_b = (const float*)d_in[6];
  const float* ln_g = (const float*)d_in[7];
  const float* ln_b = (const float*)d_in[8];
  const float* q_w = (const float*)d_in[9];
  const float* k_w = (const float*)d_in[10];
  const float* v_w = (const float*)d_in[11];
  const float* proj_w = (const float*)d_in[12];
  const float* proj_b = (const float*)d_in[13];
  float* out = (float*)d_out;

  float* ws = (float*)d_ws;
  float* xs = ws;                              // fp32 [32][196][400]
  u16* kb16 = (u16*)(ws + 2508800);            // bf16 [32][196][400]
  u16* vt16 = kb16 + 2508800;                  // bf16 [32][320][224]
  u16* qwT = vt16 + 2293760;                   // bf16 [400][320]
  u16* pwT = qwT + 128000;                     // bf16 [320][320]
                                               // total ~20.1 MB

  k_prep<<<500, 256, 0, stream>>>(q_w, proj_w, qwT, pwT);
  k_spatial<<<dim3(14, 32), 256, 0, stream>>>(x, dw_w, dw_b, pw_w, pw_b, ln_g,
                                              ln_b, xs);
  k_kv<<<dim3(7, 32), 256, 0, stream>>>(xs, k_w, v_w, kb16, vt16);
  k_attn<<<dim3(NH, 49, NB), 256, 0, stream>>>(x, qwT, kb16, vt16, out);
  k_proj<<<1568, 256, 0, stream>>>(out, pwT, proj_b);
}

// Round 3
// 780.340 us; speedup vs baseline: 10.9080x; 1.3759x over previous
//
#include <hip/hip_runtime.h>
#include <math.h>

#define NB 32
#define NN 3136
#define CD 320
#define NH 5
#define CN 400
#define NKEY 196
#define DQ 80
#define DV 64
#define SCALE_F 0.11180339887498949f

typedef __bf16 bf16x8 __attribute__((ext_vector_type(8)));
typedef float f32x4 __attribute__((ext_vector_type(4)));
typedef unsigned short u16;
typedef unsigned int u32;

__device__ __forceinline__ u16 f2bf(float f) {
  u32 u = __float_as_uint(f);
  u += 0x7fffu + ((u >> 16) & 1u);  // round-to-nearest-even
  return (u16)(u >> 16);
}

__device__ __forceinline__ bf16x8 pack8(const float4 a, const float4 b) {
  union { bf16x8 v; u16 s[8]; } u;
  u.s[0] = f2bf(a.x); u.s[1] = f2bf(a.y); u.s[2] = f2bf(a.z); u.s[3] = f2bf(a.w);
  u.s[4] = f2bf(b.x); u.s[5] = f2bf(b.y); u.s[6] = f2bf(b.z); u.s[7] = f2bf(b.w);
  return u.v;
}

// ---------------------------------------------------------------------------
// Prep: qwT bf16 [400][320]; pwT bf16 [320][320]; kvwT bf16 [720][416]
// (rows 0..399 = k_w^T, rows 400..719 = v_w^T, cols 400..415 zero).
// ---------------------------------------------------------------------------
__global__ void k_prep(const float* __restrict__ q_w,
                       const float* __restrict__ proj_w,
                       const float* __restrict__ k_w,
                       const float* __restrict__ v_w, u16* __restrict__ qwT,
                       u16* __restrict__ pwT, u16* __restrict__ kvwT) {
  const int i0 = blockIdx.x * 256 + threadIdx.x;
  const int stride = gridDim.x * 256;
  for (int idx = i0; idx < 400 * 320; idx += stride) {
    const int o = idx / 320, c = idx - o * 320;
    qwT[idx] = f2bf(q_w[(size_t)c * 400 + o]);
  }
  for (int idx = i0; idx < 320 * 320; idx += stride) {
    const int o = idx / 320, c = idx - o * 320;
    pwT[idx] = f2bf(proj_w[(size_t)c * 320 + o]);
  }
  for (int idx = i0; idx < 720 * 416; idx += stride) {
    const int o = idx / 416, c = idx - o * 416;
    float v = 0.f;
    if (c < 400) v = (o < 400) ? k_w[(size_t)c * 400 + o] : v_w[(size_t)c * 320 + (o - 400)];
    kvwT[idx] = f2bf(v);
  }
}

// ---------------------------------------------------------------------------
// Kernel 1: dwconv + 1x1 conv + LN + GELU -> xs bf16 [6272][416] (pad zeroed)
// ---------------------------------------------------------------------------
__global__ __launch_bounds__(256) void k_spatial(
    const float* __restrict__ x, const float* __restrict__ dw_w,
    const float* __restrict__ dw_b, const float* __restrict__ pw_w,
    const float* __restrict__ pw_b, const float* __restrict__ ln_g,
    const float* __restrict__ ln_b, u16* __restrict__ xs) {
  const int oh = blockIdx.x, b = blockIdx.y, tid = threadIdx.x;
  __shared__ float dwc[14][321];
  __shared__ float pre[14][401];
  const float* xb = x + (size_t)b * NN * CD;

  for (int idx = tid; idx < 14 * 320; idx += 256) {
    const int p = idx / 320, c = idx - p * 320;
    float acc = dw_b[c];
#pragma unroll
    for (int i = 0; i < 4; i++) {
#pragma unroll
      for (int j = 0; j < 4; j++) {
        const int pix = (oh * 4 + i) * 56 + p * 4 + j;
        acc += xb[(size_t)pix * CD + c] * dw_w[c * 16 + i * 4 + j];
      }
    }
    dwc[p][c] = acc;
  }
  __syncthreads();

  for (int o = tid; o < 400; o += 256) {
    float acc[14];
    const float bias = pw_b[o];
#pragma unroll
    for (int p = 0; p < 14; p++) acc[p] = bias;
    const float* wrow = pw_w + (size_t)o * 320;
    for (int c = 0; c < 320; c++) {
      const float w = wrow[c];
#pragma unroll
      for (int p = 0; p < 14; p++) acc[p] += dwc[p][c] * w;
    }
#pragma unroll
    for (int p = 0; p < 14; p++) pre[p][o] = acc[p];
  }
  __syncthreads();

  const int wave = tid >> 6, lane = tid & 63;
  for (int p = wave; p < 14; p += 4) {
    float s = 0.f, ss = 0.f;
    for (int o = lane; o < 400; o += 64) {
      const float v = pre[p][o];
      s += v;
      ss += v * v;
    }
#pragma unroll
    for (int off = 32; off > 0; off >>= 1) {
      s += __shfl_xor(s, off);
      ss += __shfl_xor(ss, off);
    }
    const float mu = s * (1.f / 400.f);
    const float var = ss * (1.f / 400.f) - mu * mu;
    const float rstd = rsqrtf(var + 1e-5f);
    u16* orow = xs + (size_t)(b * NKEY + oh * 14 + p) * 416;
    for (int o = lane; o < 400; o += 64) {
      const float v = (pre[p][o] - mu) * rstd * ln_g[o] + ln_b[o];
      orow[o] = f2bf(0.5f * v * (1.f + erff(v * 0.70710678118654752f)));
    }
    if (lane < 16) orow[400 + lane] = 0;
  }
}

// ---------------------------------------------------------------------------
// Kernel 2 (MFMA, barrier-free): [6272][416]bf16 @ kvwT^T -> kb [6272][400],
// vt [32][320][224] (v transposed, keys 196..223 left as poison — harmless).
// grid (98, 3): wave = 16 rows, N-chunk = 15 tiles of 16.
// ---------------------------------------------------------------------------
__global__ __launch_bounds__(256) void k_kv(const u16* __restrict__ xs,
                                            const u16* __restrict__ kvwT,
                                            u16* __restrict__ kb,
                                            u16* __restrict__ vt) {
  const int tid = threadIdx.x, lane = tid & 63, wv = tid >> 6;
  const int quad = lane >> 4, l15 = lane & 15;
  const int mt = blockIdx.x * 4 + wv;  // 0..391
  const f32x4 fz = {0.f, 0.f, 0.f, 0.f};

  bf16x8 A[13];
  {
    const u16* xr = xs + (size_t)(mt * 16 + l15) * 416;
#pragma unroll
    for (int ks = 0; ks < 13; ks++)
      A[ks] = *(const bf16x8*)(xr + ks * 32 + quad * 8);
  }
#pragma unroll 1
  for (int n = 0; n < 15; n++) {
    const int nt = blockIdx.y * 15 + n;
    f32x4 acc = fz;
    const u16* wr = kvwT + (size_t)(nt * 16 + l15) * 416;
#pragma unroll
    for (int ks = 0; ks < 13; ks++) {
      const bf16x8 B = *(const bf16x8*)(wr + ks * 32 + quad * 8);
      acc = __builtin_amdgcn_mfma_f32_16x16x32_bf16(A[ks], B, acc, 0, 0, 0);
    }
    const int col = nt * 16 + l15;
    if (col < 400) {
#pragma unroll
      for (int r = 0; r < 4; r++)
        kb[(size_t)(mt * 16 + quad * 4 + r) * 400 + col] = f2bf(acc[r]);
    } else {
      const int vo = col - 400;
#pragma unroll
      for (int r = 0; r < 4; r++) {
        const int row = mt * 16 + quad * 4 + r;
        const int bb = row / 196, key = row - bb * 196;
        vt[((size_t)(bb * 320 + vo)) * 224 + key] = f2bf(acc[r]);
      }
    }
  }
}

// ---------------------------------------------------------------------------
// Kernel 3 (MFMA, LDS-free, barrier-free): qb = x @ q_w  bf16 [100352][400].
// grid 784: 4 waves x 32 rows. A held in regs (x fp32 -> bf16 in-reg).
// ---------------------------------------------------------------------------
__global__ __launch_bounds__(256) void k_q(const float* __restrict__ x,
                                           const u16* __restrict__ qwT,
                                           u16* __restrict__ qb) {
  const int tid = threadIdx.x, lane = tid & 63, wv = tid >> 6;
  const int quad = lane >> 4, l15 = lane & 15;
  const int r0 = (blockIdx.x * 4 + wv) * 32;
  const f32x4 fz = {0.f, 0.f, 0.f, 0.f};

  bf16x8 A[2][10];
#pragma unroll
  for (int t = 0; t < 2; t++) {
    const float* xr = x + (size_t)(r0 + t * 16 + l15) * CD;
#pragma unroll
    for (int ks = 0; ks < 10; ks++) {
      const float4 a = *(const float4*)(xr + ks * 32 + quad * 8);
      const float4 b = *(const float4*)(xr + ks * 32 + quad * 8 + 4);
      A[t][ks] = pack8(a, b);
    }
  }
#pragma unroll 1
  for (int n = 0; n < 25; n++) {
    f32x4 acc[2] = {fz, fz};
    const u16* wr = qwT + (size_t)(n * 16 + l15) * CD;
#pragma unroll
    for (int ks = 0; ks < 10; ks++) {
      const bf16x8 B = *(const bf16x8*)(wr + ks * 32 + quad * 8);
      acc[0] = __builtin_amdgcn_mfma_f32_16x16x32_bf16(A[0][ks], B, acc[0], 0, 0, 0);
      acc[1] = __builtin_amdgcn_mfma_f32_16x16x32_bf16(A[1][ks], B, acc[1], 0, 0, 0);
    }
#pragma unroll
    for (int t = 0; t < 2; t++)
#pragma unroll
      for (int r = 0; r < 4; r++)
        qb[(size_t)(r0 + t * 16 + quad * 4 + r) * CN + n * 16 + l15] =
            f2bf(acc[t][r]);
  }
}

// ---------------------------------------------------------------------------
// Kernel 4: attention. grid (5, 49, 32), 2 barriers total.
// LDS 43264 B: Ks [208][104]; P (wave-private [16][232]) overlays dead Ks.
// q A-frags + V B-frags direct from global (L2).
// ---------------------------------------------------------------------------
__global__ __launch_bounds__(256) void k_attn(const u16* __restrict__ qb,
                                              const u16* __restrict__ kb,
                                              const u16* __restrict__ vt,
                                              float* __restrict__ out) {
  const int h = blockIdx.x, qt = blockIdx.y, b = blockIdx.z;
  const int tid = threadIdx.x, lane = tid & 63, wv = tid >> 6;
  const int quad = lane >> 4, l15 = lane & 15;
  const int q0 = qt * 64, m0 = wv * 16;
  const f32x4 fz = {0.f, 0.f, 0.f, 0.f};

  __shared__ u16 sm[208 * 104];  // 43264 B
  u16* Ks = sm;
  u16* P = sm + wv * (16 * 232);  // valid only after barrier #2

  // stage K head-slice: [196][80] -> Ks[196][104], cols 80..95 zeroed
  for (int idx = tid; idx < 196 * 12; idx += 256) {
    const int key = idx / 12, g = idx - key * 12;
    if (g < 10)
      *(uint4*)(Ks + key * 104 + g * 8) = *(const uint4*)(
          kb + ((size_t)(b * NKEY + key)) * CN + h * DQ + g * 8);
    else
      *(uint4*)(Ks + key * 104 + 80 + (g - 10) * 8) = make_uint4(0, 0, 0, 0);
  }
  __syncthreads();  // barrier #1

  // ---- S = q @ K^T  (13 key-tiles, K-dim 96; q overread covered by pad-zero B)
  f32x4 sacc[13];
#pragma unroll
  for (int n = 0; n < 13; n++) sacc[n] = fz;
  {
    const u16* qr = qb + (size_t)(b * NN + q0 + m0 + l15) * CN + h * DQ;
    bf16x8 a[3];
#pragma unroll
    for (int ks = 0; ks < 3; ks++)
      a[ks] = *(const bf16x8*)(qr + ks * 32 + quad * 8);
#pragma unroll
    for (int n = 0; n < 13; n++)
#pragma unroll
      for (int ks = 0; ks < 3; ks++) {
        const bf16x8 B =
            *(const bf16x8*)(Ks + (n * 16 + l15) * 104 + ks * 32 + quad * 8);
        sacc[n] = __builtin_amdgcn_mfma_f32_16x16x32_bf16(a[ks], B, sacc[n], 0, 0, 0);
      }
  }

  // ---- softmax in registers (keys across 13 regs x 16 lanes)
  {
    float mx[4] = {-1e30f, -1e30f, -1e30f, -1e30f};
#pragma unroll
    for (int n = 0; n < 13; n++)
#pragma unroll
      for (int r = 0; r < 4; r++) {
        const float s = (n == 12 && l15 >= 4) ? -1e30f : sacc[n][r] * SCALE_F;
        sacc[n][r] = s;
        mx[r] = fmaxf(mx[r], s);
      }
#pragma unroll
    for (int r = 0; r < 4; r++) {
      mx[r] = fmaxf(mx[r], __shfl_xor(mx[r], 1));
      mx[r] = fmaxf(mx[r], __shfl_xor(mx[r], 2));
      mx[r] = fmaxf(mx[r], __shfl_xor(mx[r], 4));
      mx[r] = fmaxf(mx[r], __shfl_xor(mx[r], 8));
    }
    float sum[4] = {0.f, 0.f, 0.f, 0.f};
#pragma unroll
    for (int n = 0; n < 13; n++)
#pragma unroll
      for (int r = 0; r < 4; r++) {
        const float e = __expf(sacc[n][r] - mx[r]);
        sacc[n][r] = e;
        sum[r] += e;
      }
#pragma unroll
    for (int r = 0; r < 4; r++) {
      sum[r] += __shfl_xor(sum[r], 1);
      sum[r] += __shfl_xor(sum[r], 2);
      sum[r] += __shfl_xor(sum[r], 4);
      sum[r] += __shfl_xor(sum[r], 8);
    }
#pragma unroll
    for (int r = 0; r < 4; r++) {
      const float inv = 1.f / sum[r];
#pragma unroll
      for (int n = 0; n < 13; n++) sacc[n][r] *= inv;
    }
  }
  __syncthreads();  // barrier #2: Ks dead, P region live

  // ---- P -> wave-private LDS [16][232] (cols 196..223 zeroed)
  {
    const int zr = lane >> 2, zc0 = 196 + (lane & 3) * 7;
#pragma unroll
    for (int t = 0; t < 7; t++) P[zr * 232 + zc0 + t] = 0;
#pragma unroll
    for (int n = 0; n < 13; n++) {
      if (n == 12 && l15 >= 4) continue;
#pragma unroll
      for (int r = 0; r < 4; r++)
        P[(quad * 4 + r) * 232 + n * 16 + l15] = f2bf(sacc[n][r]);
    }
  }

  // ---- O = P @ V   (V B-frags direct from global vt [b*320+vo][224])
  f32x4 oacc[4];
#pragma unroll
  for (int n = 0; n < 4; n++) oacc[n] = fz;
  {
    const u16* vbase = vt + (size_t)(b * 320 + h * DV) * 224;
#pragma unroll
    for (int kk = 0; kk < 7; kk++) {
      const bf16x8 a = *(const bf16x8*)(P + l15 * 232 + kk * 32 + quad * 8);
#pragma unroll
      for (int n = 0; n < 4; n++) {
        const bf16x8 B = *(const bf16x8*)(vbase + (size_t)(n * 16 + l15) * 224 +
                                          kk * 32 + quad * 8);
        oacc[n] = __builtin_amdgcn_mfma_f32_16x16x32_bf16(a, B, oacc[n], 0, 0, 0);
      }
    }
  }
#pragma unroll
  for (int n = 0; n < 4; n++)
#pragma unroll
    for (int r = 0; r < 4; r++)
      out[(size_t)(b * NN + q0 + m0 + quad * 4 + r) * CD + h * DV + n * 16 +
          l15] = oacc[n][r];
}

// ---------------------------------------------------------------------------
// Kernel 5 (LDS-free, barrier-free, in-place): out = out @ proj_w + proj_b.
// grid 784: wave = 32 rows; A-frags fully loaded to regs before any store.
// ---------------------------------------------------------------------------
__global__ __launch_bounds__(256) void k_proj(float* __restrict__ out,
                                              const u16* __restrict__ pwT,
                                              const float* __restrict__ proj_b) {
  const int tid = threadIdx.x, lane = tid & 63, wv = tid >> 6;
  const int quad = lane >> 4, l15 = lane & 15;
  const int r0 = (blockIdx.x * 4 + wv) * 32;
  const f32x4 fz = {0.f, 0.f, 0.f, 0.f};

  bf16x8 A[2][10];
#pragma unroll
  for (int t = 0; t < 2; t++) {
    const float* xr = out + (size_t)(r0 + t * 16 + l15) * CD;
#pragma unroll
    for (int ks = 0; ks < 10; ks++) {
      const float4 a = *(const float4*)(xr + ks * 32 + quad * 8);
      const float4 b = *(const float4*)(xr + ks * 32 + quad * 8 + 4);
      A[t][ks] = pack8(a, b);
    }
  }
#pragma unroll 1
  for (int n = 0; n < 20; n++) {
    f32x4 acc[2] = {fz, fz};
    const u16* wr = pwT + (size_t)(n * 16 + l15) * CD;
#pragma unroll
    for (int ks = 0; ks < 10; ks++) {
      const bf16x8 B = *(const bf16x8*)(wr + ks * 32 + quad * 8);
      acc[0] = __builtin_amdgcn_mfma_f32_16x16x32_bf16(A[0][ks], B, acc[0], 0, 0, 0);
      acc[1] = __builtin_amdgcn_mfma_f32_16x16x32_bf16(A[1][ks], B, acc[1], 0, 0, 0);
    }
    const float pb = proj_b[n * 16 + l15];
#pragma unroll
    for (int t = 0; t < 2; t++)
#pragma unroll
      for (int r = 0; r < 4; r++)
        out[(size_t)(r0 + t * 16 + quad * 4 + r) * CD + n * 16 + l15] =
            acc[t][r] + pb;
  }
}

// ---------------------------------------------------------------------------
extern "C" void kernel_launch(void* const* d_in, const int* in_sizes, int n_in,
                              void* d_out, int out_size, void* d_ws,
                              size_t ws_size, hipStream_t stream) {
  const float* x = (const float*)d_in[0];
  const float* dw_w = (const float*)d_in[3];
  const float* dw_b = (const float*)d_in[4];
  const float* pw_w = (const float*)d_in[5];
  const float* pw_b = (const float*)d_in[6];
  const float* ln_g = (const float*)d_in[7];
  const float* ln_b = (const float*)d_in[8];
  const float* q_w = (const float*)d_in[9];
  const float* k_w = (const float*)d_in[10];
  const float* v_w = (const float*)d_in[11];
  const float* proj_w = (const float*)d_in[12];
  const float* proj_b = (const float*)d_in[13];
  float* out = (float*)d_out;

  u16* w = (u16*)d_ws;
  u16* xs16 = w;                    // [6272][416]       = 2,609,152
  u16* kb16 = xs16 + 2609152;       // [6272][400]       = 2,508,800
  u16* vt16 = kb16 + 2508800;       // [32*320][224]     = 2,293,760
  u16* qb16 = vt16 + 2293760;       // [100352][400]+64  = 40,140,864
  u16* qwT = qb16 + 40140864;       // [400][320]        = 128,000
  u16* pwT = qwT + 128000;          // [320][320]        = 102,400
  u16* kvwT = pwT + 102400;         // [720][416]        = 299,520
                                    // total 96.2 MB

  k_prep<<<512, 256, 0, stream>>>(q_w, proj_w, k_w, v_w, qwT, pwT, kvwT);
  k_spatial<<<dim3(14, 32), 256, 0, stream>>>(x, dw_w, dw_b, pw_w, pw_b, ln_g,
                                              ln_b, xs16);
  k_kv<<<dim3(98, 3), 256, 0, stream>>>(xs16, kvwT, kb16, vt16);
  k_q<<<784, 256, 0, stream>>>(x, qwT, qb16);
  k_attn<<<dim3(NH, 49, NB), 256, 0, stream>>>(qb16, kb16, vt16, out);
  k_proj<<<784, 256, 0, stream>>>(out, pwT, proj_b);
}